// Round 13
// baseline (188.715 us; speedup 1.0000x reference)
//
#include <hip/hip_runtime.h>
#include <hip/hip_bf16.h>

// RelAttnBlock on MI355X (gfx950). fp32 I/O, bf16 MFMA core.
// B=8, L=1024, EMB=512, H=8, HD=64, BS=1024, M=8192.
//
// R12 = R10 (best known) + source-side bias select (HW-verified in R11):
//  - single-barrier double-buffered attn kt-loop, K/V reg-prefetch with a
//    full kt of vmcnt slack, Er 12-slot LDS ring (write/read slot-disjoint),
//    Er frag register carry strip1<-strip0, no-max softmax,
//    bpermute bias distribution now 16 shfl/strip (was 20): source lane
//    supplies (l16 >= 15-sdl ? accb[nt] : accb[nt+1]).
//  - R11's register-resident Er windows REVERTED (allocator spilled:
//    WRITE_SIZE 8->52 MB, attn +26 us).

typedef __bf16 bf16;
typedef __bf16 bf16x8 __attribute__((ext_vector_type(8)));
typedef float floatx4 __attribute__((ext_vector_type(4)));
typedef float f32x4 __attribute__((ext_vector_type(4)));

#define MFMA16 __builtin_amdgcn_mfma_f32_16x16x32_bf16

#define KS 72   // stride for 64-col bf16 staging tiles (144B = 4-bank rotation)
#define PSS 72  // Ps stride (bf16): 144B rows -> 16B-aligned b128, conflict-free
#define GS 40   // stride for 32-col bf16 GEMM staging tiles
#define TS 72   // prep transpose LDS stride

// ---- prep: tiled W transpose + Er cvt + LayerNorm, one dispatch ----
__global__ __launch_bounds__(256) void prep_ln_kernel(
    const float* __restrict__ Wq, const float* __restrict__ Wk,
    const float* __restrict__ Wv, const float* __restrict__ Wo,
    const float* __restrict__ Er,
    const float* __restrict__ x, const float* __restrict__ g,
    const float* __restrict__ bvec,
    bf16* __restrict__ wt, bf16* __restrict__ er_b, bf16* __restrict__ h) {
  __shared__ __align__(16) bf16 T[64 * TS];
  int blk = blockIdx.x;
  int tid = threadIdx.x;
  if (blk < 256) {
    // 64x64 tile transpose: wt[w][n][k] = W[k][n], coalesced both ways.
    int w = blk >> 6, rem = blk & 63;
    int r0 = (rem >> 3) << 6, c0 = (rem & 7) << 6;   // k-range, n-range
    const float* W = (w == 0) ? Wq : (w == 1) ? Wk : (w == 2) ? Wv : Wo;
    int row = tid >> 2, cc = (tid & 3) << 4;
    const f32x4* src = (const f32x4*)(W + (r0 + row) * 512 + c0 + cc);
#pragma unroll
    for (int q2 = 0; q2 < 4; q2++) {
      f32x4 v = src[q2];
#pragma unroll
      for (int j = 0; j < 4; j++)
        T[(cc + q2 * 4 + j) * TS + row] = (bf16)v[j];
    }
    __syncthreads();
    int nloc = tid >> 2, kc = (tid & 3) << 4;
    bf16x8 a = *(const bf16x8*)(T + nloc * TS + kc);
    bf16x8 b = *(const bf16x8*)(T + nloc * TS + kc + 8);
    bf16* dst = wt + (w << 18) + (c0 + nloc) * 512 + r0 + kc;
    *(bf16x8*)dst = a;
    *(bf16x8*)(dst + 8) = b;
    return;
  }
  if (blk < 2304) {
    int e = (blk - 256) * 256 + tid;                 // 8*1024*64
    er_b[e] = (bf16)Er[e];
    return;
  }
  int row = (blk - 2304) * 4 + (tid >> 6);           // 8192 rows
  int lane = tid & 63;
  const f32x4* xr = (const f32x4*)(x + row * 512 + lane * 8);
  f32x4 v0 = xr[0], v1 = xr[1];
  float f[8] = {v0[0], v0[1], v0[2], v0[3], v1[0], v1[1], v1[2], v1[3]};
  float s = 0.f, ss = 0.f;
#pragma unroll
  for (int i = 0; i < 8; i++) { s += f[i]; ss += f[i] * f[i]; }
#pragma unroll
  for (int m = 1; m < 64; m <<= 1) { s += __shfl_xor(s, m); ss += __shfl_xor(ss, m); }
  float mean = s * (1.0f / 512.0f);
  float var = ss * (1.0f / 512.0f) - mean * mean;
  float inv = rsqrtf(var + 1e-5f);
  const f32x4* gr = (const f32x4*)(g + lane * 8);
  const f32x4* br = (const f32x4*)(bvec + lane * 8);
  f32x4 g0 = gr[0], g1 = gr[1], b0 = br[0], b1 = br[1];
  float gg[8] = {g0[0], g0[1], g0[2], g0[3], g1[0], g1[1], g1[2], g1[3]};
  float bb[8] = {b0[0], b0[1], b0[2], b0[3], b1[0], b1[1], b1[2], b1[3]};
  bf16x8 o;
#pragma unroll
  for (int i = 0; i < 8; i++)
    o[i] = (bf16)((f[i] - mean) * inv * gg[i] + bb[i]);
  *(bf16x8*)(h + row * 512 + lane * 8) = o;
}

// C/D layout: col = lane&15, row = (lane>>4)*4 + reg.
// A layout: m = lane&15, k = (lane>>4)*8 + j.  B layout: n = lane&15, same k.

__global__ __launch_bounds__(256) void qkv_gemm(
    const bf16* __restrict__ A,      // h: 8192 x 512
    const bf16* __restrict__ wt,     // [3][512][512] n-major
    const float* __restrict__ bq, const float* __restrict__ bk,
    const float* __restrict__ bv,
    bf16* __restrict__ q_ws, bf16* __restrict__ k_ws, bf16* __restrict__ vt_ws) {
  // smem: As/Bs during K-loop, reused as V-transpose buffer in w==2 epilogue.
  __shared__ __align__(16) bf16 smem[64 * 264];      // 33792 B
  bf16* As = smem;
  bf16* Bs = smem + 128 * GS;
  int m0 = blockIdx.x * 128;
  int ng0 = blockIdx.y * 128;         // 0..1408, within one 512-block
  int w = ng0 >> 9;                   // 0=Q 1=K 2=V (uniform per block)
  int n0 = ng0 & 511;
  const bf16* Bt = wt + (w << 18);
  int tid = threadIdx.x;
  int wave = tid >> 6, lane = tid & 63, quad = lane >> 4, l16 = lane & 15;
  int mq = (wave >> 1) * 64, nq = (wave & 1) * 64;

  floatx4 acc[4][4] = {};
  for (int k0 = 0; k0 < 512; k0 += 32) {
    int r = tid >> 1, c = (tid & 1) * 16;
    *(bf16x8*)(As + r * GS + c)     = *(const bf16x8*)(A + (m0 + r) * 512 + k0 + c);
    *(bf16x8*)(As + r * GS + c + 8) = *(const bf16x8*)(A + (m0 + r) * 512 + k0 + c + 8);
    *(bf16x8*)(Bs + r * GS + c)     = *(const bf16x8*)(Bt + (n0 + r) * 512 + k0 + c);
    *(bf16x8*)(Bs + r * GS + c + 8) = *(const bf16x8*)(Bt + (n0 + r) * 512 + k0 + c + 8);
    __syncthreads();
    bf16x8 a[4], b[4];
#pragma unroll
    for (int mt = 0; mt < 4; mt++)
      a[mt] = *(const bf16x8*)(As + (mq + mt * 16 + l16) * GS + quad * 8);
#pragma unroll
    for (int nt = 0; nt < 4; nt++)
      b[nt] = *(const bf16x8*)(Bs + (nq + nt * 16 + l16) * GS + quad * 8);
#pragma unroll
    for (int mt = 0; mt < 4; mt++)
#pragma unroll
      for (int nt = 0; nt < 4; nt++)
        acc[mt][nt] = MFMA16(a[mt], b[nt], acc[mt][nt], 0, 0, 0);
    __syncthreads();
  }

  if (w == 2) {
    // V: write C-tiles (+bias) into LDS transposed, then coalesced stores.
#pragma unroll
    for (int nt = 0; nt < 4; nt++) {
      int col = n0 + nq + nt * 16 + l16;
      float bb = bv[col];
      int d = col & 63;
#pragma unroll
      for (int mt = 0; mt < 4; mt++)
#pragma unroll
        for (int r = 0; r < 4; r++) {
          int lloc = mq + mt * 16 + quad * 4 + r;
          smem[d * 264 + (wave & 1) * 128 + lloc] = (bf16)(acc[mt][nt][r] + bb);
        }
    }
    __syncthreads();
    int b_ = m0 >> 10, l0g = m0 & 1023;
    int dloc = tid >> 4, lc = (tid & 15) * 8;
#pragma unroll
    for (int h2 = 0; h2 < 2; h2++) {
      int bh = b_ * 8 + ((n0 + h2 * 64) >> 6);
#pragma unroll
      for (int dd = 0; dd < 4; dd++) {
        int d = dd * 16 + dloc;
        bf16x8 v = *(const bf16x8*)(smem + d * 264 + h2 * 128 + lc);
        *(bf16x8*)(vt_ws + (bh << 16) + (d << 10) + l0g + lc) = v;
      }
    }
    return;
  }

  const float* bias = (w == 0) ? bq : bk;
#pragma unroll
  for (int nt = 0; nt < 4; nt++) {
    int col = n0 + nq + nt * 16 + l16;   // 0..511 within this W
    float bb = bias[col];
    int hh = col >> 6, d = col & 63;
#pragma unroll
    for (int mt = 0; mt < 4; mt++) {
#pragma unroll
      for (int r = 0; r < 4; r++) {
        int mrow = m0 + mq + mt * 16 + quad * 4 + r;   // 0..8191
        int b_ = mrow >> 10, l = mrow & 1023;
        int bh = b_ * 8 + hh;
        float v = acc[mt][nt][r] + bb;
        if (w == 0) q_ws[(bh << 16) + (l << 6) + d] = (bf16)v;
        else        k_ws[(bh << 16) + (l << 6) + d] = (bf16)(v * 0.125f);
      }
    }
  }
}

__global__ __launch_bounds__(256, 2) void attn_kernel(
    const bf16* __restrict__ q_ws, const bf16* __restrict__ k_ws,
    const bf16* __restrict__ vt_ws, const bf16* __restrict__ Er,
    bf16* __restrict__ o_ws) {
  __shared__ __align__(16) bf16 Ks_s[2][64 * KS];       // 18.4 KB dbuf [key][d]
  __shared__ __align__(16) bf16 Vs[2][64 * KS];         // 18.4 KB dbuf [d][key]
  __shared__ __align__(16) bf16 Ers[192 * KS];          // 27.6 KB 12-slot ring
  __shared__ __align__(16) bf16 Ps[4][16 * PSS];        //  9.2 KB per-wave

  int qt = blockIdx.x;       // 0..7 (128-row Q tiles)
  int bh = blockIdx.y;       // 0..63
  int hh = bh & 7;
  int l0 = qt << 7;
  int tid = threadIdx.x, wave = tid >> 6, lane = tid & 63;
  int quad = lane >> 4, l16 = lane & 15;

  // Two 16-row strips per wave: rows l0 + strip*64 + wave*16 + [0,16).
  bf16x8 aq0[2], aq1[2];
#pragma unroll
  for (int strip = 0; strip < 2; strip++) {
    const bf16* qb = q_ws + (bh << 16) + ((l0 + strip * 64 + wave * 16 + l16) << 6);
    aq0[strip] = *(const bf16x8*)(qb + quad * 8);
    aq1[strip] = *(const bf16x8*)(qb + 32 + quad * 8);
  }

  const bf16* kbh = k_ws + (bh << 16);
  const bf16* vbh = vt_ws + (bh << 16);
  const bf16* ebh = Er + (hh << 16);
  bf16* pw = Ps[wave];

  float l_run[2][4] = {};
  floatx4 acc_o[2][4] = {};

  // Er ring: tile Tt (rows e0+Tt*16+[0,16)) in slot Tt%12.
  // Window at kt = tiles 4kt..4kt+11; strip window t0 = 7-4*strip-wave.
  // IDENTITY: strip0's tiles at kt == strip1's at kt+1 (register carry).
  // SAFETY: writes at kt+1 top hit slots sb..sb+3 (mod 12); LDS reads during
  // kt only touch slots >= sb (disjoint from next write set after sb+=4).
  int e0 = -l0 - 127 + 2048;
  // prime slots 0..7 (tiles 0..7 = rows 0..127) global->LDS
#pragma unroll
  for (int i = 0; i < 4; i++) {
    int o = tid + i * 256;              // 0..1023
    int row = o >> 3, ch = (o & 7) * 8;
    int grow = (e0 + row) & 1023;
    *(bf16x8*)(Ers + row * KS + ch) = *(const bf16x8*)(ebh + (grow << 6) + ch);
  }
  // prefetch kt=0 staging into registers: K(0), V(0), Er tiles 8..11
  int sr0 = tid >> 3, sc0 = (tid & 7) * 8;   // rows 0..31
  int sr1 = sr0 + 32;                        // rows 32..63
  bf16x8 pk[2], pvv[2], pe[2];
  pk[0]  = *(const bf16x8*)(kbh + (sr0 << 6) + sc0);
  pk[1]  = *(const bf16x8*)(kbh + (sr1 << 6) + sc0);
  pvv[0] = *(const bf16x8*)(vbh + (sr0 << 10) + sc0);
  pvv[1] = *(const bf16x8*)(vbh + (sr1 << 10) + sc0);
  pe[0]  = *(const bf16x8*)(ebh + (((e0 + 128 + sr0) & 1023) << 6) + sc0);
  pe[1]  = *(const bf16x8*)(ebh + (((e0 + 128 + sr1) & 1023) << 6) + sc0);
  __syncthreads();                          // priming writes visible
  // prime carried Er frags = strip1's kt=0 window (tiles 3-w..7-w, staged)
  bf16x8 ec0[5], ec1[5];
#pragma unroll
  for (int i = 0; i < 5; i++) {
    int tt = 3 - wave + i;                  // 0..7
    const bf16* er = Ers + ((tt << 4) + l16) * KS + quad * 8;
    ec0[i] = *(const bf16x8*)er;
    ec1[i] = *(const bf16x8*)(er + 32);
  }
  int sb = 0;                               // (4*kt) % 12

  for (int kt = 0; kt < 16; kt++) {
    int k0 = kt * 64;
    int bsel = kt & 1;
    // ---- ds_write prefetched staging (regs loaded one full kt ago) ----
    bf16* Kb = Ks_s[bsel];
    bf16* Vb = Vs[bsel];
    *(bf16x8*)(Kb + sr0 * KS + sc0) = pk[0];
    *(bf16x8*)(Kb + sr1 * KS + sc0) = pk[1];
    *(bf16x8*)(Vb + sr0 * KS + sc0) = pvv[0];
    *(bf16x8*)(Vb + sr1 * KS + sc0) = pvv[1];
    {
      int s8 = sb + 8; if (s8 >= 12) s8 -= 12;       // slot of tile 4kt+8
      bf16* Eb = Ers + (s8 << 4) * KS;               // 64 rows, no wrap
      *(bf16x8*)(Eb + sr0 * KS + sc0) = pe[0];
      *(bf16x8*)(Eb + sr1 * KS + sc0) = pe[1];
    }
    __syncthreads();                                 // the ONLY barrier per kt

    // ---- hoisted K/V B-fragments, shared by both strips ----
    bf16x8 kb0[4], kb1[4], vb0[4], vb1[4];
#pragma unroll
    for (int nt = 0; nt < 4; nt++) {
      const bf16* kr = Kb + (nt * 16 + l16) * KS + quad * 8;
      kb0[nt] = *(const bf16x8*)kr;
      kb1[nt] = *(const bf16x8*)(kr + 32);
      const bf16* vr = Vb + (nt * 16 + l16) * KS + quad * 8;
      vb0[nt] = *(const bf16x8*)vr;
      vb1[nt] = *(const bf16x8*)(vr + 32);
    }

    // ---- prefetch kt+1 staging (full compute phase of vmcnt slack) ----
    {
      int kn = (kt + 1) & 15;                        // kt=15: dead, in-bounds
      int kn0 = kn * 64;
      pk[0]  = *(const bf16x8*)(kbh + ((kn0 + sr0) << 6) + sc0);
      pk[1]  = *(const bf16x8*)(kbh + ((kn0 + sr1) << 6) + sc0);
      pvv[0] = *(const bf16x8*)(vbh + (sr0 << 10) + kn0 + sc0);
      pvv[1] = *(const bf16x8*)(vbh + (sr1 << 10) + kn0 + sc0);
      pe[0]  = *(const bf16x8*)(ebh + (((e0 + 192 + k0 + sr0) & 1023) << 6) + sc0);
      pe[1]  = *(const bf16x8*)(ebh + (((e0 + 192 + k0 + sr1) & 1023) << 6) + sc0);
    }

    // strips processed 1 then 0: strip1 consumes carried ec, strip0 loads
    // fresh ec (which become next kt's strip1 frags).
#pragma unroll
    for (int pass = 0; pass < 2; pass++) {
      int strip = 1 - pass;
      // ---- S = Q K'^T ----
      floatx4 acc_s[4] = {};
#pragma unroll
      for (int nt = 0; nt < 4; nt++) {
        acc_s[nt] = MFMA16(aq0[strip], kb0[nt], acc_s[nt], 0, 0, 0);
        acc_s[nt] = MFMA16(aq1[strip], kb1[nt], acc_s[nt], 0, 0, 0);
      }
      // ---- rel-bias 5-tile cover from carried frags ----
      floatx4 accb[5];
#pragma unroll
      for (int t = 0; t < 5; t++) {
        floatx4 a = {};
        a = MFMA16(aq0[strip], ec0[t], a, 0, 0, 0);
        a = MFMA16(aq1[strip], ec1[t], a, 0, 0, 0);
        accb[t] = a;
      }
      if (pass == 0) {
        // refill ec = strip0's window (tiles sb+7-w .. sb+11-w, staged)
#pragma unroll
        for (int i = 0; i < 5; i++) {
          int tt = sb + 7 - wave + i; if (tt >= 12) tt -= 12;
          const bf16* er = Ers + ((tt << 4) + l16) * KS + quad * 8;
          ec0[i] = *(const bf16x8*)er;
          ec1[i] = *(const bf16x8*)(er + 32);
        }
      }
      // ---- bias distribution: source-side select + ONE shfl per (nt,r)
      //      (R11-verified): src lane supplies accb[nt] if its
      //      l16 >= 15-sdl, else accb[nt+1]; dest pulls from
      //      (quad<<4)|cc, cc = dd<=0 ? 15+dd : dd-1, dd = l16-sdl. ----
      float pv[4][4];
#pragma unroll
      for (int r = 0; r < 4; r++) {
        int sdl = quad * 4 + r;
        int dd = l16 - sdl;
        int cc = (dd <= 0) ? (15 + dd) : (dd - 1);
        int src = (quad << 4) | cc;
        bool hi = (l16 >= 15 - sdl);
#pragma unroll
        for (int nt = 0; nt < 4; nt++) {
          float sel = hi ? accb[nt][r] : accb[nt + 1][r];
          float b = __shfl(sel, src);
          pv[nt][r] = __expf(acc_s[nt][r] + b);
        }
      }
#pragma unroll
      for (int r = 0; r < 4; r++)
        l_run[strip][r] += pv[0][r] + pv[1][r] + pv[2][r] + pv[3][r];
      // ---- P: C-layout -> LDS -> A-layout (wave-private, in-order DS) ----
#pragma unroll
      for (int nt = 0; nt < 4; nt++)
#pragma unroll
        for (int r = 0; r < 4; r++)
          pw[(quad * 4 + r) * PSS + nt * 16 + l16] = (bf16)pv[nt][r];
      bf16x8 ap0 = *(const bf16x8*)(pw + l16 * PSS + quad * 8);
      bf16x8 ap1 = *(const bf16x8*)(pw + l16 * PSS + 32 + quad * 8);
      // ---- O += P V ----
#pragma unroll
      for (int dt = 0; dt < 4; dt++) {
        acc_o[strip][dt] = MFMA16(ap0, vb0[dt], acc_o[strip][dt], 0, 0, 0);
        acc_o[strip][dt] = MFMA16(ap1, vb1[dt], acc_o[strip][dt], 0, 0, 0);
      }
    }
    sb += 4; if (sb >= 12) sb -= 12;
    // no trailing barrier: dbuf K/V + ring slot disjointness make it safe
  }

  // deferred row-sum reduction + normalize + store
#pragma unroll
  for (int strip = 0; strip < 2; strip++) {
    float invl[4];
#pragma unroll
    for (int r = 0; r < 4; r++) {
      float lr = l_run[strip][r];
#pragma unroll
      for (int m = 1; m < 16; m <<= 1) lr += __shfl_xor(lr, m);
      invl[r] = 1.0f / lr;
    }
#pragma unroll
    for (int dt = 0; dt < 4; dt++) {
      int col = (hh << 6) + dt * 16 + l16;
#pragma unroll
      for (int r = 0; r < 4; r++) {
        int row = ((bh >> 3) << 10) + l0 + strip * 64 + wave * 16 + quad * 4 + r;
        o_ws[row * 512 + col] = (bf16)(acc_o[strip][dt][r] * invl[r]);
      }
    }
  }
}

__global__ __launch_bounds__(256) void out_gemm(
    const bf16* __restrict__ A,      // o_ws: 8192 x 512
    const bf16* __restrict__ Bt,     // WoT n-major
    const float* __restrict__ bo, float* __restrict__ out) {
  __shared__ __align__(16) bf16 As[128 * GS];
  __shared__ __align__(16) bf16 Bs[128 * GS];
  int m0 = blockIdx.x * 128;
  int n0 = blockIdx.y * 128;
  int tid = threadIdx.x;
  int wave = tid >> 6, lane = tid & 63, quad = lane >> 4, l16 = lane & 15;
  int mq = (wave >> 1) * 64, nq = (wave & 1) * 64;

  floatx4 acc[4][4] = {};
  for (int k0 = 0; k0 < 512; k0 += 32) {
    int r = tid >> 1, c = (tid & 1) * 16;
    *(bf16x8*)(As + r * GS + c)     = *(const bf16x8*)(A + (m0 + r) * 512 + k0 + c);
    *(bf16x8*)(As + r * GS + c + 8) = *(const bf16x8*)(A + (m0 + r) * 512 + k0 + c + 8);
    *(bf16x8*)(Bs + r * GS + c)     = *(const bf16x8*)(Bt + (n0 + r) * 512 + k0 + c);
    *(bf16x8*)(Bs + r * GS + c + 8) = *(const bf16x8*)(Bt + (n0 + r) * 512 + k0 + c + 8);
    __syncthreads();
    bf16x8 a[4], b[4];
#pragma unroll
    for (int mt = 0; mt < 4; mt++)
      a[mt] = *(const bf16x8*)(As + (mq + mt * 16 + l16) * GS + quad * 8);
#pragma unroll
    for (int nt = 0; nt < 4; nt++)
      b[nt] = *(const bf16x8*)(Bs + (nq + nt * 16 + l16) * GS + quad * 8);
#pragma unroll
    for (int mt = 0; mt < 4; mt++)
#pragma unroll
      for (int nt = 0; nt < 4; nt++)
        acc[mt][nt] = MFMA16(a[mt], b[nt], acc[mt][nt], 0, 0, 0);
    __syncthreads();
  }
#pragma unroll
  for (int nt = 0; nt < 4; nt++) {
    int col = n0 + nq + nt * 16 + l16;
    float bb = bo[col];
#pragma unroll
    for (int mt = 0; mt < 4; mt++) {
#pragma unroll
      for (int r = 0; r < 4; r++) {
        int mrow = m0 + mq + mt * 16 + quad * 4 + r;
        out[mrow * 512 + col] = acc[mt][nt][r] + bb;
      }
    }
  }
}

extern "C" void kernel_launch(void* const* d_in, const int* in_sizes, int n_in,
                              void* d_out, int out_size, void* d_ws, size_t ws_size,
                              hipStream_t stream) {
  const float* x    = (const float*)d_in[0];
  const float* ln_g = (const float*)d_in[1];
  const float* ln_b = (const float*)d_in[2];
  const float* Wq   = (const float*)d_in[3];
  const float* bq   = (const float*)d_in[4];
  const float* Wk   = (const float*)d_in[5];
  const float* bk   = (const float*)d_in[6];
  const float* Wv   = (const float*)d_in[7];
  const float* bv   = (const float*)d_in[8];
  const float* Wo   = (const float*)d_in[9];
  const float* bo   = (const float*)d_in[10];
  const float* Er   = (const float*)d_in[11];
  float* out = (float*)d_out;

  char* ws = (char*)d_ws;
  bf16* wt    = (bf16*)(ws);                       // 2MB: [4][512][512]
  bf16* er_b  = (bf16*)(ws + (2u << 20));          // 1MB
  bf16* h     = (bf16*)(ws + (3u << 20));          // 8MB
  bf16* o_ws  = h;                                 // alias (h dead by then)
  bf16* q_ws  = (bf16*)(ws + (11u << 20));         // 8MB
  bf16* k_ws  = (bf16*)(ws + (19u << 20));         // 8MB
  bf16* vt_ws = (bf16*)(ws + (27u << 20));         // 8MB

  prep_ln_kernel<<<4352, 256, 0, stream>>>(Wq, Wk, Wv, Wo, Er, x, ln_g, ln_b,
                                           wt, er_b, h);
  qkv_gemm<<<dim3(64, 12), 256, 0, stream>>>(h, wt, bq, bk, bv, q_ws, k_ws, vt_ws);
  attn_kernel<<<dim3(8, 64), 256, 0, stream>>>(q_ws, k_ws, vt_ws, er_b, o_ws);
  out_gemm<<<dim3(64, 4), 256, 0, stream>>>(o_ws, wt + 3 * 262144, bo, out);
}

// Round 14
// 188.383 us; speedup vs baseline: 1.0018x; 1.0018x over previous
//
#include <hip/hip_runtime.h>
#include <hip/hip_bf16.h>

// RelAttnBlock on MI355X (gfx950). fp32 I/O, bf16 MFMA core.
// B=8, L=1024, EMB=512, H=8, HD=64, BS=1024, M=8192.
//
// R14 = R12/13 (best known) + two low-risk changes:
//  - attn XCD-locality swizzle: grid (bh=64, qt=8) so the 8 qt-blocks
//    sharing one bh's K/V/Er land on the SAME XCD (linear id = bh + 64*qt,
//    XCD = id%8 = bh%8). Per-XCD working set 8 bh x ~384KB = 3MB <= 4MB L2.
//    (Old grid spread same-bh blocks across all 8 XCDs -> 81MB HBM fetch
//    for a 24MB logical set; latency-bound kernel pays ~900cyc HBM misses.)
//  - prep: Er fp32->bf16 conversion vectorized x8 (2048 -> 256 blocks).
//  Attn core identical to R12: 1-barrier dbuf kt-loop, K/V reg-prefetch,
//  12-slot Er LDS ring, Er frag carry, source-side-select bias bpermute,
//  no-max softmax, PSS=72.

typedef __bf16 bf16;
typedef __bf16 bf16x8 __attribute__((ext_vector_type(8)));
typedef float floatx4 __attribute__((ext_vector_type(4)));
typedef float f32x4 __attribute__((ext_vector_type(4)));

#define MFMA16 __builtin_amdgcn_mfma_f32_16x16x32_bf16

#define KS 72   // stride for 64-col bf16 staging tiles (144B = 4-bank rotation)
#define PSS 72  // Ps stride (bf16): 144B rows -> 16B-aligned b128, conflict-free
#define GS 40   // stride for 32-col bf16 GEMM staging tiles
#define TS 72   // prep transpose LDS stride

// ---- prep: tiled W transpose + Er cvt (x8) + LayerNorm, one dispatch ----
__global__ __launch_bounds__(256) void prep_ln_kernel(
    const float* __restrict__ Wq, const float* __restrict__ Wk,
    const float* __restrict__ Wv, const float* __restrict__ Wo,
    const float* __restrict__ Er,
    const float* __restrict__ x, const float* __restrict__ g,
    const float* __restrict__ bvec,
    bf16* __restrict__ wt, bf16* __restrict__ er_b, bf16* __restrict__ h) {
  __shared__ __align__(16) bf16 T[64 * TS];
  int blk = blockIdx.x;
  int tid = threadIdx.x;
  if (blk < 256) {
    // 64x64 tile transpose: wt[w][n][k] = W[k][n], coalesced both ways.
    int w = blk >> 6, rem = blk & 63;
    int r0 = (rem >> 3) << 6, c0 = (rem & 7) << 6;   // k-range, n-range
    const float* W = (w == 0) ? Wq : (w == 1) ? Wk : (w == 2) ? Wv : Wo;
    int row = tid >> 2, cc = (tid & 3) << 4;
    const f32x4* src = (const f32x4*)(W + (r0 + row) * 512 + c0 + cc);
#pragma unroll
    for (int q2 = 0; q2 < 4; q2++) {
      f32x4 v = src[q2];
#pragma unroll
      for (int j = 0; j < 4; j++)
        T[(cc + q2 * 4 + j) * TS + row] = (bf16)v[j];
    }
    __syncthreads();
    int nloc = tid >> 2, kc = (tid & 3) << 4;
    bf16x8 a = *(const bf16x8*)(T + nloc * TS + kc);
    bf16x8 b = *(const bf16x8*)(T + nloc * TS + kc + 8);
    bf16* dst = wt + (w << 18) + (c0 + nloc) * 512 + r0 + kc;
    *(bf16x8*)dst = a;
    *(bf16x8*)(dst + 8) = b;
    return;
  }
  if (blk < 512) {
    int e = ((blk - 256) * 256 + tid) * 8;           // 8*1024*64 total
    const f32x4* s4 = (const f32x4*)(Er + e);
    f32x4 v0 = s4[0], v1 = s4[1];
    bf16x8 o;
    o[0] = (bf16)v0[0]; o[1] = (bf16)v0[1]; o[2] = (bf16)v0[2]; o[3] = (bf16)v0[3];
    o[4] = (bf16)v1[0]; o[5] = (bf16)v1[1]; o[6] = (bf16)v1[2]; o[7] = (bf16)v1[3];
    *(bf16x8*)(er_b + e) = o;
    return;
  }
  int row = (blk - 512) * 4 + (tid >> 6);            // 8192 rows
  int lane = tid & 63;
  const f32x4* xr = (const f32x4*)(x + row * 512 + lane * 8);
  f32x4 v0 = xr[0], v1 = xr[1];
  float f[8] = {v0[0], v0[1], v0[2], v0[3], v1[0], v1[1], v1[2], v1[3]};
  float s = 0.f, ss = 0.f;
#pragma unroll
  for (int i = 0; i < 8; i++) { s += f[i]; ss += f[i] * f[i]; }
#pragma unroll
  for (int m = 1; m < 64; m <<= 1) { s += __shfl_xor(s, m); ss += __shfl_xor(ss, m); }
  float mean = s * (1.0f / 512.0f);
  float var = ss * (1.0f / 512.0f) - mean * mean;
  float inv = rsqrtf(var + 1e-5f);
  const f32x4* gr = (const f32x4*)(g + lane * 8);
  const f32x4* br = (const f32x4*)(bvec + lane * 8);
  f32x4 g0 = gr[0], g1 = gr[1], b0 = br[0], b1 = br[1];
  float gg[8] = {g0[0], g0[1], g0[2], g0[3], g1[0], g1[1], g1[2], g1[3]};
  float bb[8] = {b0[0], b0[1], b0[2], b0[3], b1[0], b1[1], b1[2], b1[3]};
  bf16x8 o;
#pragma unroll
  for (int i = 0; i < 8; i++)
    o[i] = (bf16)((f[i] - mean) * inv * gg[i] + bb[i]);
  *(bf16x8*)(h + row * 512 + lane * 8) = o;
}

// C/D layout: col = lane&15, row = (lane>>4)*4 + reg.
// A layout: m = lane&15, k = (lane>>4)*8 + j.  B layout: n = lane&15, same k.

__global__ __launch_bounds__(256) void qkv_gemm(
    const bf16* __restrict__ A,      // h: 8192 x 512
    const bf16* __restrict__ wt,     // [3][512][512] n-major
    const float* __restrict__ bq, const float* __restrict__ bk,
    const float* __restrict__ bv,
    bf16* __restrict__ q_ws, bf16* __restrict__ k_ws, bf16* __restrict__ vt_ws) {
  // smem: As/Bs during K-loop, reused as V-transpose buffer in w==2 epilogue.
  __shared__ __align__(16) bf16 smem[64 * 264];      // 33792 B
  bf16* As = smem;
  bf16* Bs = smem + 128 * GS;
  int m0 = blockIdx.x * 128;
  int ng0 = blockIdx.y * 128;         // 0..1408, within one 512-block
  int w = ng0 >> 9;                   // 0=Q 1=K 2=V (uniform per block)
  int n0 = ng0 & 511;
  const bf16* Bt = wt + (w << 18);
  int tid = threadIdx.x;
  int wave = tid >> 6, lane = tid & 63, quad = lane >> 4, l16 = lane & 15;
  int mq = (wave >> 1) * 64, nq = (wave & 1) * 64;

  floatx4 acc[4][4] = {};
  for (int k0 = 0; k0 < 512; k0 += 32) {
    int r = tid >> 1, c = (tid & 1) * 16;
    *(bf16x8*)(As + r * GS + c)     = *(const bf16x8*)(A + (m0 + r) * 512 + k0 + c);
    *(bf16x8*)(As + r * GS + c + 8) = *(const bf16x8*)(A + (m0 + r) * 512 + k0 + c + 8);
    *(bf16x8*)(Bs + r * GS + c)     = *(const bf16x8*)(Bt + (n0 + r) * 512 + k0 + c);
    *(bf16x8*)(Bs + r * GS + c + 8) = *(const bf16x8*)(Bt + (n0 + r) * 512 + k0 + c + 8);
    __syncthreads();
    bf16x8 a[4], b[4];
#pragma unroll
    for (int mt = 0; mt < 4; mt++)
      a[mt] = *(const bf16x8*)(As + (mq + mt * 16 + l16) * GS + quad * 8);
#pragma unroll
    for (int nt = 0; nt < 4; nt++)
      b[nt] = *(const bf16x8*)(Bs + (nq + nt * 16 + l16) * GS + quad * 8);
#pragma unroll
    for (int mt = 0; mt < 4; mt++)
#pragma unroll
      for (int nt = 0; nt < 4; nt++)
        acc[mt][nt] = MFMA16(a[mt], b[nt], acc[mt][nt], 0, 0, 0);
    __syncthreads();
  }

  if (w == 2) {
    // V: write C-tiles (+bias) into LDS transposed, then coalesced stores.
#pragma unroll
    for (int nt = 0; nt < 4; nt++) {
      int col = n0 + nq + nt * 16 + l16;
      float bb = bv[col];
      int d = col & 63;
#pragma unroll
      for (int mt = 0; mt < 4; mt++)
#pragma unroll
        for (int r = 0; r < 4; r++) {
          int lloc = mq + mt * 16 + quad * 4 + r;
          smem[d * 264 + (wave & 1) * 128 + lloc] = (bf16)(acc[mt][nt][r] + bb);
        }
    }
    __syncthreads();
    int b_ = m0 >> 10, l0g = m0 & 1023;
    int dloc = tid >> 4, lc = (tid & 15) * 8;
#pragma unroll
    for (int h2 = 0; h2 < 2; h2++) {
      int bh = b_ * 8 + ((n0 + h2 * 64) >> 6);
#pragma unroll
      for (int dd = 0; dd < 4; dd++) {
        int d = dd * 16 + dloc;
        bf16x8 v = *(const bf16x8*)(smem + d * 264 + h2 * 128 + lc);
        *(bf16x8*)(vt_ws + (bh << 16) + (d << 10) + l0g + lc) = v;
      }
    }
    return;
  }

  const float* bias = (w == 0) ? bq : bk;
#pragma unroll
  for (int nt = 0; nt < 4; nt++) {
    int col = n0 + nq + nt * 16 + l16;   // 0..511 within this W
    float bb = bias[col];
    int hh = col >> 6, d = col & 63;
#pragma unroll
    for (int mt = 0; mt < 4; mt++) {
#pragma unroll
      for (int r = 0; r < 4; r++) {
        int mrow = m0 + mq + mt * 16 + quad * 4 + r;   // 0..8191
        int b_ = mrow >> 10, l = mrow & 1023;
        int bh = b_ * 8 + hh;
        float v = acc[mt][nt][r] + bb;
        if (w == 0) q_ws[(bh << 16) + (l << 6) + d] = (bf16)v;
        else        k_ws[(bh << 16) + (l << 6) + d] = (bf16)(v * 0.125f);
      }
    }
  }
}

__global__ __launch_bounds__(256, 2) void attn_kernel(
    const bf16* __restrict__ q_ws, const bf16* __restrict__ k_ws,
    const bf16* __restrict__ vt_ws, const bf16* __restrict__ Er,
    bf16* __restrict__ o_ws) {
  __shared__ __align__(16) bf16 Ks_s[2][64 * KS];       // 18.4 KB dbuf [key][d]
  __shared__ __align__(16) bf16 Vs[2][64 * KS];         // 18.4 KB dbuf [d][key]
  __shared__ __align__(16) bf16 Ers[192 * KS];          // 27.6 KB 12-slot ring
  __shared__ __align__(16) bf16 Ps[4][16 * PSS];        //  9.2 KB per-wave

  // XCD-locality swizzle: x = bh (64), y = qt (8). linear id = bh + 64*qt
  // -> XCD = bh % 8 for all 8 qt-blocks of a bh -> K/V/Er L2-resident.
  int bh = blockIdx.x;       // 0..63
  int qt = blockIdx.y;       // 0..7 (128-row Q tiles)
  int hh = bh & 7;
  int l0 = qt << 7;
  int tid = threadIdx.x, wave = tid >> 6, lane = tid & 63;
  int quad = lane >> 4, l16 = lane & 15;

  // Two 16-row strips per wave: rows l0 + strip*64 + wave*16 + [0,16).
  bf16x8 aq0[2], aq1[2];
#pragma unroll
  for (int strip = 0; strip < 2; strip++) {
    const bf16* qb = q_ws + (bh << 16) + ((l0 + strip * 64 + wave * 16 + l16) << 6);
    aq0[strip] = *(const bf16x8*)(qb + quad * 8);
    aq1[strip] = *(const bf16x8*)(qb + 32 + quad * 8);
  }

  const bf16* kbh = k_ws + (bh << 16);
  const bf16* vbh = vt_ws + (bh << 16);
  const bf16* ebh = Er + (hh << 16);
  bf16* pw = Ps[wave];

  float l_run[2][4] = {};
  floatx4 acc_o[2][4] = {};

  // Er ring: tile Tt (rows e0+Tt*16+[0,16)) in slot Tt%12.
  // Window at kt = tiles 4kt..4kt+11; strip window t0 = 7-4*strip-wave.
  // IDENTITY: strip0's tiles at kt == strip1's at kt+1 (register carry).
  int e0 = -l0 - 127 + 2048;
  // prime slots 0..7 (tiles 0..7 = rows 0..127) global->LDS
#pragma unroll
  for (int i = 0; i < 4; i++) {
    int o = tid + i * 256;              // 0..1023
    int row = o >> 3, ch = (o & 7) * 8;
    int grow = (e0 + row) & 1023;
    *(bf16x8*)(Ers + row * KS + ch) = *(const bf16x8*)(ebh + (grow << 6) + ch);
  }
  // prefetch kt=0 staging into registers: K(0), V(0), Er tiles 8..11
  int sr0 = tid >> 3, sc0 = (tid & 7) * 8;   // rows 0..31
  int sr1 = sr0 + 32;                        // rows 32..63
  bf16x8 pk[2], pvv[2], pe[2];
  pk[0]  = *(const bf16x8*)(kbh + (sr0 << 6) + sc0);
  pk[1]  = *(const bf16x8*)(kbh + (sr1 << 6) + sc0);
  pvv[0] = *(const bf16x8*)(vbh + (sr0 << 10) + sc0);
  pvv[1] = *(const bf16x8*)(vbh + (sr1 << 10) + sc0);
  pe[0]  = *(const bf16x8*)(ebh + (((e0 + 128 + sr0) & 1023) << 6) + sc0);
  pe[1]  = *(const bf16x8*)(ebh + (((e0 + 128 + sr1) & 1023) << 6) + sc0);
  __syncthreads();                          // priming writes visible
  // prime carried Er frags = strip1's kt=0 window (tiles 3-w..7-w, staged)
  bf16x8 ec0[5], ec1[5];
#pragma unroll
  for (int i = 0; i < 5; i++) {
    int tt = 3 - wave + i;                  // 0..7
    const bf16* er = Ers + ((tt << 4) + l16) * KS + quad * 8;
    ec0[i] = *(const bf16x8*)er;
    ec1[i] = *(const bf16x8*)(er + 32);
  }
  int sb = 0;                               // (4*kt) % 12

  for (int kt = 0; kt < 16; kt++) {
    int k0 = kt * 64;
    int bsel = kt & 1;
    // ---- ds_write prefetched staging (regs loaded one full kt ago) ----
    bf16* Kb = Ks_s[bsel];
    bf16* Vb = Vs[bsel];
    *(bf16x8*)(Kb + sr0 * KS + sc0) = pk[0];
    *(bf16x8*)(Kb + sr1 * KS + sc0) = pk[1];
    *(bf16x8*)(Vb + sr0 * KS + sc0) = pvv[0];
    *(bf16x8*)(Vb + sr1 * KS + sc0) = pvv[1];
    {
      int s8 = sb + 8; if (s8 >= 12) s8 -= 12;       // slot of tile 4kt+8
      bf16* Eb = Ers + (s8 << 4) * KS;               // 64 rows, no wrap
      *(bf16x8*)(Eb + sr0 * KS + sc0) = pe[0];
      *(bf16x8*)(Eb + sr1 * KS + sc0) = pe[1];
    }
    __syncthreads();                                 // the ONLY barrier per kt

    // ---- hoisted K/V B-fragments, shared by both strips ----
    bf16x8 kb0[4], kb1[4], vb0[4], vb1[4];
#pragma unroll
    for (int nt = 0; nt < 4; nt++) {
      const bf16* kr = Kb + (nt * 16 + l16) * KS + quad * 8;
      kb0[nt] = *(const bf16x8*)kr;
      kb1[nt] = *(const bf16x8*)(kr + 32);
      const bf16* vr = Vb + (nt * 16 + l16) * KS + quad * 8;
      vb0[nt] = *(const bf16x8*)vr;
      vb1[nt] = *(const bf16x8*)(vr + 32);
    }

    // ---- prefetch kt+1 staging (full compute phase of vmcnt slack) ----
    {
      int kn = (kt + 1) & 15;                        // kt=15: dead, in-bounds
      int kn0 = kn * 64;
      pk[0]  = *(const bf16x8*)(kbh + ((kn0 + sr0) << 6) + sc0);
      pk[1]  = *(const bf16x8*)(kbh + ((kn0 + sr1) << 6) + sc0);
      pvv[0] = *(const bf16x8*)(vbh + (sr0 << 10) + kn0 + sc0);
      pvv[1] = *(const bf16x8*)(vbh + (sr1 << 10) + kn0 + sc0);
      pe[0]  = *(const bf16x8*)(ebh + (((e0 + 192 + k0 + sr0) & 1023) << 6) + sc0);
      pe[1]  = *(const bf16x8*)(ebh + (((e0 + 192 + k0 + sr1) & 1023) << 6) + sc0);
    }

    // strips processed 1 then 0: strip1 consumes carried ec, strip0 loads
    // fresh ec (which become next kt's strip1 frags).
#pragma unroll
    for (int pass = 0; pass < 2; pass++) {
      int strip = 1 - pass;
      // ---- S = Q K'^T ----
      floatx4 acc_s[4] = {};
#pragma unroll
      for (int nt = 0; nt < 4; nt++) {
        acc_s[nt] = MFMA16(aq0[strip], kb0[nt], acc_s[nt], 0, 0, 0);
        acc_s[nt] = MFMA16(aq1[strip], kb1[nt], acc_s[nt], 0, 0, 0);
      }
      // ---- rel-bias 5-tile cover from carried frags ----
      floatx4 accb[5];
#pragma unroll
      for (int t = 0; t < 5; t++) {
        floatx4 a = {};
        a = MFMA16(aq0[strip], ec0[t], a, 0, 0, 0);
        a = MFMA16(aq1[strip], ec1[t], a, 0, 0, 0);
        accb[t] = a;
      }
      if (pass == 0) {
        // refill ec = strip0's window (tiles sb+7-w .. sb+11-w, staged)
#pragma unroll
        for (int i = 0; i < 5; i++) {
          int tt = sb + 7 - wave + i; if (tt >= 12) tt -= 12;
          const bf16* er = Ers + ((tt << 4) + l16) * KS + quad * 8;
          ec0[i] = *(const bf16x8*)er;
          ec1[i] = *(const bf16x8*)(er + 32);
        }
      }
      // ---- bias distribution: source-side select + ONE shfl per (nt,r) ----
      float pv[4][4];
#pragma unroll
      for (int r = 0; r < 4; r++) {
        int sdl = quad * 4 + r;
        int dd = l16 - sdl;
        int cc = (dd <= 0) ? (15 + dd) : (dd - 1);
        int src = (quad << 4) | cc;
        bool hi = (l16 >= 15 - sdl);
#pragma unroll
        for (int nt = 0; nt < 4; nt++) {
          float sel = hi ? accb[nt][r] : accb[nt + 1][r];
          float b = __shfl(sel, src);
          pv[nt][r] = __expf(acc_s[nt][r] + b);
        }
      }
#pragma unroll
      for (int r = 0; r < 4; r++)
        l_run[strip][r] += pv[0][r] + pv[1][r] + pv[2][r] + pv[3][r];
      // ---- P: C-layout -> LDS -> A-layout (wave-private, in-order DS) ----
#pragma unroll
      for (int nt = 0; nt < 4; nt++)
#pragma unroll
        for (int r = 0; r < 4; r++)
          pw[(quad * 4 + r) * PSS + nt * 16 + l16] = (bf16)pv[nt][r];
      bf16x8 ap0 = *(const bf16x8*)(pw + l16 * PSS + quad * 8);
      bf16x8 ap1 = *(const bf16x8*)(pw + l16 * PSS + 32 + quad * 8);
      // ---- O += P V ----
#pragma unroll
      for (int dt = 0; dt < 4; dt++) {
        acc_o[strip][dt] = MFMA16(ap0, vb0[dt], acc_o[strip][dt], 0, 0, 0);
        acc_o[strip][dt] = MFMA16(ap1, vb1[dt], acc_o[strip][dt], 0, 0, 0);
      }
    }
    sb += 4; if (sb >= 12) sb -= 12;
    // no trailing barrier: dbuf K/V + ring slot disjointness make it safe
  }

  // deferred row-sum reduction + normalize + store
#pragma unroll
  for (int strip = 0; strip < 2; strip++) {
    float invl[4];
#pragma unroll
    for (int r = 0; r < 4; r++) {
      float lr = l_run[strip][r];
#pragma unroll
      for (int m = 1; m < 16; m <<= 1) lr += __shfl_xor(lr, m);
      invl[r] = 1.0f / lr;
    }
#pragma unroll
    for (int dt = 0; dt < 4; dt++) {
      int col = (hh << 6) + dt * 16 + l16;
#pragma unroll
      for (int r = 0; r < 4; r++) {
        int row = ((bh >> 3) << 10) + l0 + strip * 64 + wave * 16 + quad * 4 + r;
        o_ws[row * 512 + col] = (bf16)(acc_o[strip][dt][r] * invl[r]);
      }
    }
  }
}

__global__ __launch_bounds__(256) void out_gemm(
    const bf16* __restrict__ A,      // o_ws: 8192 x 512
    const bf16* __restrict__ Bt,     // WoT n-major
    const float* __restrict__ bo, float* __restrict__ out) {
  __shared__ __align__(16) bf16 As[128 * GS];
  __shared__ __align__(16) bf16 Bs[128 * GS];
  int m0 = blockIdx.x * 128;
  int n0 = blockIdx.y * 128;
  int tid = threadIdx.x;
  int wave = tid >> 6, lane = tid & 63, quad = lane >> 4, l16 = lane & 15;
  int mq = (wave >> 1) * 64, nq = (wave & 1) * 64;

  floatx4 acc[4][4] = {};
  for (int k0 = 0; k0 < 512; k0 += 32) {
    int r = tid >> 1, c = (tid & 1) * 16;
    *(bf16x8*)(As + r * GS + c)     = *(const bf16x8*)(A + (m0 + r) * 512 + k0 + c);
    *(bf16x8*)(As + r * GS + c + 8) = *(const bf16x8*)(A + (m0 + r) * 512 + k0 + c + 8);
    *(bf16x8*)(Bs + r * GS + c)     = *(const bf16x8*)(Bt + (n0 + r) * 512 + k0 + c);
    *(bf16x8*)(Bs + r * GS + c + 8) = *(const bf16x8*)(Bt + (n0 + r) * 512 + k0 + c + 8);
    __syncthreads();
    bf16x8 a[4], b[4];
#pragma unroll
    for (int mt = 0; mt < 4; mt++)
      a[mt] = *(const bf16x8*)(As + (mq + mt * 16 + l16) * GS + quad * 8);
#pragma unroll
    for (int nt = 0; nt < 4; nt++)
      b[nt] = *(const bf16x8*)(Bs + (nq + nt * 16 + l16) * GS + quad * 8);
#pragma unroll
    for (int mt = 0; mt < 4; mt++)
#pragma unroll
      for (int nt = 0; nt < 4; nt++)
        acc[mt][nt] = MFMA16(a[mt], b[nt], acc[mt][nt], 0, 0, 0);
    __syncthreads();
  }
#pragma unroll
  for (int nt = 0; nt < 4; nt++) {
    int col = n0 + nq + nt * 16 + l16;
    float bb = bo[col];
#pragma unroll
    for (int mt = 0; mt < 4; mt++) {
#pragma unroll
      for (int r = 0; r < 4; r++) {
        int mrow = m0 + mq + mt * 16 + quad * 4 + r;
        out[mrow * 512 + col] = acc[mt][nt][r] + bb;
      }
    }
  }
}

extern "C" void kernel_launch(void* const* d_in, const int* in_sizes, int n_in,
                              void* d_out, int out_size, void* d_ws, size_t ws_size,
                              hipStream_t stream) {
  const float* x    = (const float*)d_in[0];
  const float* ln_g = (const float*)d_in[1];
  const float* ln_b = (const float*)d_in[2];
  const float* Wq   = (const float*)d_in[3];
  const float* bq   = (const float*)d_in[4];
  const float* Wk   = (const float*)d_in[5];
  const float* bk   = (const float*)d_in[6];
  const float* Wv   = (const float*)d_in[7];
  const float* bv   = (const float*)d_in[8];
  const float* Wo   = (const float*)d_in[9];
  const float* bo   = (const float*)d_in[10];
  const float* Er   = (const float*)d_in[11];
  float* out = (float*)d_out;

  char* ws = (char*)d_ws;
  bf16* wt    = (bf16*)(ws);                       // 2MB: [4][512][512]
  bf16* er_b  = (bf16*)(ws + (2u << 20));          // 1MB
  bf16* h     = (bf16*)(ws + (3u << 20));          // 8MB
  bf16* o_ws  = h;                                 // alias (h dead by then)
  bf16* q_ws  = (bf16*)(ws + (11u << 20));         // 8MB
  bf16* k_ws  = (bf16*)(ws + (19u << 20));         // 8MB
  bf16* vt_ws = (bf16*)(ws + (27u << 20));         // 8MB

  prep_ln_kernel<<<2560, 256, 0, stream>>>(Wq, Wk, Wv, Wo, Er, x, ln_g, ln_b,
                                           wt, er_b, h);
  qkv_gemm<<<dim3(64, 12), 256, 0, stream>>>(h, wt, bq, bk, bv, q_ws, k_ws, vt_ws);
  attn_kernel<<<dim3(64, 8), 256, 0, stream>>>(q_ws, k_ws, vt_ws, er_b, o_ws);
  out_gemm<<<dim3(64, 4), 256, 0, stream>>>(o_ws, wt + 3 * 262144, bo, out);
}